// Round 9
// baseline (379.603 us; speedup 1.0000x reference)
//
#include <hip/hip_runtime.h>
#include <cstdint>

#define TPB 256

typedef __attribute__((ext_vector_type(8))) short bf16x8;
typedef __attribute__((ext_vector_type(4))) float f32x4;

__device__ inline unsigned short f2bf(float f) {
  unsigned u = __float_as_uint(f);
  u += 0x7fffu + ((u >> 16) & 1u);
  return (unsigned short)(u >> 16);
}
__device__ inline float bf2f(unsigned short h) {
  return __uint_as_float(((unsigned)h) << 16);
}

__device__ inline void gload_lds16(const void* g, void* l) {
  __builtin_amdgcn_global_load_lds(
      (const __attribute__((address_space(1))) unsigned int*)g,
      (__attribute__((address_space(3))) unsigned int*)l, 16, 0, 0);
}

// accumulate 8 bf16 features (packed in int4) scaled by nv into acc[0..7]
__device__ inline void acc_bf8(float* acc, int4 raw, float nv) {
  acc[0] += nv * __uint_as_float(((unsigned)raw.x) << 16);
  acc[1] += nv * __uint_as_float(((unsigned)raw.x) & 0xffff0000u);
  acc[2] += nv * __uint_as_float(((unsigned)raw.y) << 16);
  acc[3] += nv * __uint_as_float(((unsigned)raw.y) & 0xffff0000u);
  acc[4] += nv * __uint_as_float(((unsigned)raw.z) << 16);
  acc[5] += nv * __uint_as_float(((unsigned)raw.z) & 0xffff0000u);
  acc[6] += nv * __uint_as_float(((unsigned)raw.w) << 16);
  acc[7] += nv * __uint_as_float(((unsigned)raw.w) & 0xffff0000u);
}

// ================= x -> bf16 =================

__global__ void k_x2bf(const float* __restrict__ x, unsigned short* __restrict__ xb,
                       long total8) {
  long i = blockIdx.x * (long)blockDim.x + threadIdx.x;
  if (i >= total8) return;
  const float4* p = reinterpret_cast<const float4*>(x + i * 8);
  float4 a = p[0], b = p[1];
  unsigned short h[8];
  h[0] = f2bf(a.x); h[1] = f2bf(a.y); h[2] = f2bf(a.z); h[3] = f2bf(a.w);
  h[4] = f2bf(b.x); h[5] = f2bf(b.y); h[6] = f2bf(b.z); h[7] = f2bf(b.w);
  *reinterpret_cast<int4*>(xb + i * 8) = *(int4*)h;
}

// ================= binned CSR build =================
// bin = col>>6 (1024 bins x 64 nodes). k = blockIdx&7 (~XCD) sub-bins.

__global__ void k_bincnt(const int* __restrict__ col, int* __restrict__ bcnt8, int E) {
  int e = blockIdx.x * blockDim.x + threadIdx.x;
  if (e >= E) return;
  int k = blockIdx.x & 7;
  atomicAdd(&bcnt8[k * 1024 + (col[e] >> 6)], 1);
}

// single block 256 threads: scan 1024 bins x 8 k -> cursors base8, binstart[1025], ptr[n]=E
__global__ void k_binscan(const int* __restrict__ bcnt8, int* __restrict__ base8,
                          int* __restrict__ binstart, int* __restrict__ ptrv, int n) {
  __shared__ int psum[256];
  int t = threadIdx.x;
  int loc = 0;
  for (int b = t * 4; b < t * 4 + 4; ++b)
#pragma unroll
    for (int k = 0; k < 8; ++k) loc += bcnt8[k * 1024 + b];
  psum[t] = loc;
  __syncthreads();
  for (int st = 1; st < 256; st <<= 1) {
    int a = (t >= st) ? psum[t - st] : 0;
    __syncthreads();
    psum[t] += a;
    __syncthreads();
  }
  int run = psum[t] - loc;  // exclusive prefix of this thread's chunk
  for (int b = t * 4; b < t * 4 + 4; ++b) {
    binstart[b] = run;
#pragma unroll
    for (int k = 0; k < 8; ++k) {
      base8[k * 1024 + b] = run;
      run += bcnt8[k * 1024 + b];
    }
  }
  if (t == 255) { binstart[1024] = run; ptrv[n] = run; }
}

// scatter edges into bin regions (sequential per (k,bin) cursor).
// tmp record: (row | lc<<16, w)
__global__ void k_binscatter(const int* __restrict__ row, const int* __restrict__ col,
                             const float* __restrict__ w, int* __restrict__ bcur8,
                             int2* __restrict__ tmp, int E) {
  int e = blockIdx.x * blockDim.x + threadIdx.x;
  if (e >= E) return;
  int k = blockIdx.x & 7;
  int c = col[e];
  int p = atomicAdd(&bcur8[k * 1024 + (c >> 6)], 1);
  tmp[p] = make_int2(row[e] | ((c & 63) << 16), __float_as_int(w[e]));
}

// per bin: per-node count+degree in LDS -> ptr[node], dis[node]
__global__ __launch_bounds__(256) void k_pass2a(const int2* __restrict__ tmp,
                                                const int* __restrict__ binstart,
                                                int* __restrict__ ptrv,
                                                float* __restrict__ dis) {
  __shared__ int lcnt[64];
  __shared__ float ldeg[64];
  __shared__ int loff[64];
  const int b = blockIdx.x;
  const int t = threadIdx.x;
  if (t < 64) { lcnt[t] = 0; ldeg[t] = 0.f; }
  __syncthreads();
  const int s = binstart[b], epn = binstart[b + 1];
  for (int i = s + t; i < epn; i += 256) {
    int2 d = tmp[i];
    int lc = (d.x >> 16) & 63;
    atomicAdd(&lcnt[lc], 1);
    atomicAdd(&ldeg[lc], __int_as_float(d.y));
  }
  __syncthreads();
  if (t == 0) {
    int r = 0;
    for (int j = 0; j < 64; ++j) { loff[j] = r; r += lcnt[j]; }
  }
  __syncthreads();
  if (t < 64) {
    int node = b * 64 + t;
    ptrv[node] = s + loff[t];
    dis[node] = rsqrtf(1.0f + ldeg[t]);
  }
}

// per bin: final scatter within 8KB window, norm fused
__global__ __launch_bounds__(256) void k_pass2b(const int2* __restrict__ tmp,
                                                const int* __restrict__ binstart,
                                                const int* __restrict__ ptrv,
                                                const float* __restrict__ dis,
                                                int2* __restrict__ edat) {
  __shared__ int lcur[64];
  __shared__ float ldis[64];
  const int b = blockIdx.x;
  const int t = threadIdx.x;
  if (t < 64) {
    int node = b * 64 + t;
    lcur[t] = ptrv[node];
    ldis[t] = dis[node];
  }
  __syncthreads();
  const int s = binstart[b], epn = binstart[b + 1];
  for (int i = s + t; i < epn; i += 256) {
    int2 d = tmp[i];
    int r = d.x & 0xFFFF;
    int lc = (d.x >> 16) & 63;
    float nv = dis[r] * __int_as_float(d.y) * ldis[lc];
    int p = atomicAdd(&lcur[lc], 1);
    edat[p] = make_int2(r, __float_as_int(nv));
  }
}

// ================= fused W fragment prep (hi/lo split kept) =================

__device__ inline void wprep_one(const float* __restrict__ W, unsigned short* __restrict__ Fh,
                                 unsigned short* __restrict__ Fl, int t, int M) {
  int l = t & 63;
  int rest = t >> 6;
  int nt16 = M >> 4;
  int c0t = rest % nt16;
  int ks = rest / nt16;
  int colg = c0t * 16 + (l & 15);
  int krow = (ks << 5) + ((l >> 4) << 3);
  size_t ob = (size_t)t * 8;
#pragma unroll
  for (int j = 0; j < 8; ++j) {
    float f = W[(size_t)(krow + j) * M + colg];
    unsigned short h = f2bf(f);
    Fh[ob + j] = h;
    Fl[ob + j] = f2bf(f - bf2f(h));
  }
}

__global__ void k_wprep3(const float* __restrict__ W1, const float* __restrict__ W2,
                         const float* __restrict__ W3,
                         unsigned short* __restrict__ f1h, unsigned short* __restrict__ f1l,
                         unsigned short* __restrict__ f2h, unsigned short* __restrict__ f2l,
                         unsigned short* __restrict__ f3h, unsigned short* __restrict__ f3l) {
  int t = blockIdx.x * blockDim.x + threadIdx.x;
  if (t < 4096) wprep_one(W1, f1h, f1l, t, 256);
  else if (t < 8192) wprep_one(W2, f2h, f2l, t - 4096, 128);
  else if (t < 9216) wprep_one(W3, f3h, f3l, t - 8192, 64);
}

// ================= gather aggregation (bf16 src, bf16 out) =================

template<int GL, bool RELU, bool BIAS>
__global__ __launch_bounds__(256) void k_gagg(const int* __restrict__ ptr,
                                              const int2* __restrict__ edat,
                                              const unsigned short* __restrict__ src,
                                              const float* __restrict__ dis,
                                              const float* __restrict__ bias,
                                              unsigned short* __restrict__ outp, int n) {
  constexpr int F = GL * 8;
  constexpr int GPB = 256 / GL;
  const int gid = blockIdx.x * GPB + threadIdx.x / GL;
  const int lane = threadIdx.x % GL;
  if (gid >= n) return;
  const int e0 = ptr[gid], e1 = ptr[gid + 1];
  float d = dis[gid];
  float ss = d * d;
  float acc[8] = {0.f, 0.f, 0.f, 0.f, 0.f, 0.f, 0.f, 0.f};
  {
    int4 raw = *reinterpret_cast<const int4*>(src + (size_t)gid * F + lane * 8);
    acc_bf8(acc, raw, ss);
  }
  int e = e0;
  for (; e + 8 <= e1; e += 8) {
    int2 ed[8];
#pragma unroll
    for (int u = 0; u < 8; ++u) ed[u] = edat[e + u];
    int4 raw[8];
#pragma unroll
    for (int u = 0; u < 8; ++u)
      raw[u] = *reinterpret_cast<const int4*>(src + (size_t)ed[u].x * F + lane * 8);
#pragma unroll
    for (int u = 0; u < 8; ++u) acc_bf8(acc, raw[u], __int_as_float(ed[u].y));
  }
  for (; e + 4 <= e1; e += 4) {
    int2 ed[4];
#pragma unroll
    for (int u = 0; u < 4; ++u) ed[u] = edat[e + u];
    int4 raw[4];
#pragma unroll
    for (int u = 0; u < 4; ++u)
      raw[u] = *reinterpret_cast<const int4*>(src + (size_t)ed[u].x * F + lane * 8);
#pragma unroll
    for (int u = 0; u < 4; ++u) acc_bf8(acc, raw[u], __int_as_float(ed[u].y));
  }
  for (; e < e1; ++e) {
    int2 ed = edat[e];
    int4 raw = *reinterpret_cast<const int4*>(src + (size_t)ed.x * F + lane * 8);
    acc_bf8(acc, raw, __int_as_float(ed.y));
  }
  if (BIAS) {
#pragma unroll
    for (int j = 0; j < 8; ++j) acc[j] += bias[lane * 8 + j];
  }
  if (RELU) {
#pragma unroll
    for (int j = 0; j < 8; ++j) acc[j] = fmaxf(acc[j], 0.f);
  }
  unsigned short hv[8];
#pragma unroll
  for (int j = 0; j < 8; ++j) hv[j] = f2bf(acc[j]);
  *reinterpret_cast<int4*>(outp + (size_t)gid * F + lane * 8) = *(int4*)hv;
}

// Layer-3 aggregation: t3 bf16 [n,64] -> padded f32 out [ng, npg+1, 64], +b3.
__global__ __launch_bounds__(256) void k_gagg_out(const int* __restrict__ ptr,
                                                  const int2* __restrict__ edat,
                                                  const unsigned short* __restrict__ t3,
                                                  const float* __restrict__ dis,
                                                  const float* __restrict__ b3,
                                                  float* __restrict__ out,
                                                  const int* __restrict__ ngp,
                                                  int n, int nrows) {
  const int gid = blockIdx.x * 32 + threadIdx.x / 8;
  const int lane = threadIdx.x % 8;
  if (gid >= nrows) return;
  const int ng = *ngp;
  const int npg = n / ng;
  const int g = gid / (npg + 1);
  const int r = gid - g * (npg + 1);
  float acc[8] = {0.f, 0.f, 0.f, 0.f, 0.f, 0.f, 0.f, 0.f};
  if (r < npg) {
    const int i = g * npg + r;
    const int e0 = ptr[i], e1 = ptr[i + 1];
    float d = dis[i];
    float ss = d * d;
    int4 sraw = *reinterpret_cast<const int4*>(t3 + (size_t)i * 64 + lane * 8);
    acc_bf8(acc, sraw, ss);
    int e = e0;
    for (; e + 8 <= e1; e += 8) {
      int2 ed[8];
#pragma unroll
      for (int u = 0; u < 8; ++u) ed[u] = edat[e + u];
      int4 raw[8];
#pragma unroll
      for (int u = 0; u < 8; ++u)
        raw[u] = *reinterpret_cast<const int4*>(t3 + (size_t)ed[u].x * 64 + lane * 8);
#pragma unroll
      for (int u = 0; u < 8; ++u) acc_bf8(acc, raw[u], __int_as_float(ed[u].y));
    }
    for (; e + 4 <= e1; e += 4) {
      int2 ed[4];
#pragma unroll
      for (int u = 0; u < 4; ++u) ed[u] = edat[e + u];
      int4 raw[4];
#pragma unroll
      for (int u = 0; u < 4; ++u)
        raw[u] = *reinterpret_cast<const int4*>(t3 + (size_t)ed[u].x * 64 + lane * 8);
#pragma unroll
      for (int u = 0; u < 4; ++u) acc_bf8(acc, raw[u], __int_as_float(ed[u].y));
    }
    for (; e < e1; ++e) {
      int2 ed = edat[e];
      int4 raw = *reinterpret_cast<const int4*>(t3 + (size_t)ed.x * 64 + lane * 8);
      acc_bf8(acc, raw, __int_as_float(ed.y));
    }
#pragma unroll
    for (int j = 0; j < 8; ++j) acc[j] += b3[lane * 8 + j];
  }
  float4 o0 = make_float4(acc[0], acc[1], acc[2], acc[3]);
  float4 o1 = make_float4(acc[4], acc[5], acc[6], acc[7]);
  *reinterpret_cast<float4*>(out + (size_t)gid * 64 + lane * 8) = o0;
  *reinterpret_cast<float4*>(out + (size_t)gid * 64 + lane * 8 + 4) = o1;
}

// ================= bf16-A x split-W MFMA GEMM =================

template<bool BIAS, bool RELU>
__global__ __launch_bounds__(256) void gemm_mfma(
    const unsigned short* __restrict__ A,
    const unsigned short* __restrict__ BfHi, const unsigned short* __restrict__ BfLo,
    const float* __restrict__ bias,
    unsigned short* __restrict__ C, int K, int M) {
  __shared__ unsigned short AL[4096];
  const int tid = threadIdx.x;
  const int l = tid & 63;
  const int w = tid >> 6;
  const int m0 = blockIdx.x * 128;
  const int wmt = (w >> 1) * 4;
  const int wn = (w & 1) * 2;
  const int ntile0 = blockIdx.y * 4 + wn;
  const int nt16 = M >> 4;

  f32x4 acc[4][2];
#pragma unroll
  for (int a = 0; a < 4; ++a)
#pragma unroll
    for (int b = 0; b < 2; ++b) acc[a][b] = f32x4{0.f, 0.f, 0.f, 0.f};

  const int nks = K >> 5;
  for (int ks = 0; ks < nks; ++ks) {
    if (ks) __syncthreads();
#pragma unroll
    for (int rr = 0; rr < 2; ++rr) {
      int s = rr * 256 + tid;
      int mt = s >> 6, sl = s & 63;
      size_t grow = (size_t)(m0 + mt * 16 + (sl & 15)) * K + (ks << 5) + ((sl >> 4) << 3);
      gload_lds16(A + grow, &AL[(size_t)s * 8]);
    }
    int4 braw[2][2];
#pragma unroll
    for (int nt = 0; nt < 2; ++nt) {
      size_t bidx = ((size_t)(ks * nt16 + ntile0 + nt) * 64 + l) * 8;
      braw[nt][0] = *reinterpret_cast<const int4*>(BfHi + bidx);
      braw[nt][1] = *reinterpret_cast<const int4*>(BfLo + bidx);
    }
    asm volatile("s_waitcnt vmcnt(0)" ::: "memory");
    __syncthreads();
#pragma unroll
    for (int mt = 0; mt < 4; ++mt) {
      int slot = (wmt + mt) * 64 + l;
      bf16x8 av = __builtin_bit_cast(bf16x8, *reinterpret_cast<const int4*>(&AL[(size_t)slot * 8]));
#pragma unroll
      for (int nt = 0; nt < 2; ++nt) {
        bf16x8 bh = __builtin_bit_cast(bf16x8, braw[nt][0]);
        bf16x8 bl = __builtin_bit_cast(bf16x8, braw[nt][1]);
        acc[mt][nt] = __builtin_amdgcn_mfma_f32_16x16x32_bf16(av, bl, acc[mt][nt], 0, 0, 0);
        acc[mt][nt] = __builtin_amdgcn_mfma_f32_16x16x32_bf16(av, bh, acc[mt][nt], 0, 0, 0);
      }
    }
  }
#pragma unroll
  for (int mt = 0; mt < 4; ++mt) {
    int rowb = m0 + (wmt + mt) * 16 + ((l >> 4) << 2);
#pragma unroll
    for (int nt = 0; nt < 2; ++nt) {
      int colg = (ntile0 + nt) * 16 + (l & 15);
      float bv = 0.f;
      if (BIAS) bv = bias[colg];
#pragma unroll
      for (int i = 0; i < 4; ++i) {
        float v = acc[mt][nt][i] + bv;
        if (RELU) v = fmaxf(v, 0.f);
        C[(size_t)(rowb + i) * M + colg] = f2bf(v);
      }
    }
  }
}

// ================= launch =================

static inline int nblk(long work, int tpb = TPB) { return (int)((work + tpb - 1) / tpb); }

extern "C" void kernel_launch(void* const* d_in, const int* in_sizes, int n_in,
                              void* d_out, int out_size, void* d_ws, size_t ws_size,
                              hipStream_t stream) {
  const float* x  = (const float*)d_in[0];
  const int*   ei = (const int*)d_in[1];
  const float* ew = (const float*)d_in[2];
  const int*  ngp = (const int*)d_in[3];
  const float* W1 = (const float*)d_in[4];
  const float* b1 = (const float*)d_in[5];
  const float* W2 = (const float*)d_in[6];
  const float* b2 = (const float*)d_in[7];
  const float* W3 = (const float*)d_in[8];
  const float* b3 = (const float*)d_in[9];
  float* out = (float*)d_out;

  const int n = in_sizes[0] / 128;  // 65536
  const int E = in_sizes[2];        // 1048576
  const int* row = ei;
  const int* col = ei + E;

  const size_t MB = 1024 * 1024;
  char* W8 = (char*)d_ws;
  int2* edat = (int2*)W8;                              // 0..8 MB
  int2* tmp  = (int2*)(W8 + 8 * MB);                   // 8..16 MB
  int* bcnt8 = (int*)(W8 + 16 * MB);                   // 8192 int
  int* base8 = bcnt8 + 8192;                           // 8192 int
  int* binstart = base8 + 8192;                        // 1025 int
  int* ptrv  = binstart + 1025 + 3;                    // n+1 int
  float* dis = (float*)(ptrv + n + 1);                 // n
  unsigned short* xb  = (unsigned short*)(W8 + 17 * MB);  // 16 MB
  unsigned short* t1u = (unsigned short*)(W8 + 33 * MB);  // 16 MB
  unsigned short* t2u = t1u;                              // alias
  unsigned short* t3u = t1u;                              // alias
  unsigned short* h1u = (unsigned short*)(W8 + 49 * MB);  // 32 MB
  unsigned short* h2u = h1u;                              // alias (h1 dead)
  unsigned short* w1fh = (unsigned short*)(W8 + 81 * MB);
  unsigned short* w1fl = w1fh + 32768;
  unsigned short* w2fh = w1fl + 32768;
  unsigned short* w2fl = w2fh + 32768;
  unsigned short* w3fh = w2fl + 32768;
  unsigned short* w3fl = w3fh + 8192;

  // ---- binned CSR build
  hipMemsetAsync(bcnt8, 0, 8192 * sizeof(int), stream);
  k_x2bf<<<nblk((long)n * 16), TPB, 0, stream>>>(x, xb, (long)n * 16);
  k_bincnt<<<nblk(E), TPB, 0, stream>>>(col, bcnt8, E);
  k_binscan<<<1, 256, 0, stream>>>(bcnt8, base8, binstart, ptrv, n);
  k_binscatter<<<nblk(E), TPB, 0, stream>>>(row, col, ew, base8, tmp, E);
  k_pass2a<<<1024, 256, 0, stream>>>(tmp, binstart, ptrv, dis);
  k_pass2b<<<1024, 256, 0, stream>>>(tmp, binstart, ptrv, dis, edat);

  // ---- weight fragment prep
  k_wprep3<<<nblk(9216), TPB, 0, stream>>>(W1, W2, W3, w1fh, w1fl, w2fh, w2fl, w3fh, w3fl);

  // ---- layer 1: t1 = A(xb); h1 = relu(t1@W1+b1)
  k_gagg<16, false, false><<<nblk((long)n * 16), TPB, 0, stream>>>(
      ptrv, edat, xb, dis, nullptr, t1u, n);
  {
    dim3 g(n / 128, 256 / 64);
    gemm_mfma<true, true><<<g, 256, 0, stream>>>(t1u, w1fh, w1fl, b1, h1u, 128, 256);
  }

  // ---- layer 2: t2 = h1@W2; h2 = relu(A(t2)+b2)
  {
    dim3 g(n / 128, 128 / 64);
    gemm_mfma<false, false><<<g, 256, 0, stream>>>(h1u, w2fh, w2fl, nullptr, t2u, 256, 128);
  }
  k_gagg<16, true, true><<<nblk((long)n * 16), TPB, 0, stream>>>(
      ptrv, edat, t2u, dis, b2, h2u, n);

  // ---- layer 3: t3 = h2@W3; out = A(t3)+b3 into padded layout
  {
    dim3 g(n / 128, 64 / 64);
    gemm_mfma<false, false><<<g, 256, 0, stream>>>(h2u, w3fh, w3fl, nullptr, t3u, 128, 64);
  }
  const int nrows = out_size / 64;
  k_gagg_out<<<nblk((long)nrows * 8), TPB, 0, stream>>>(
      ptrv, edat, t3u, dis, b3, out, ngp, n, nrows);
}